// Round 13
// baseline (12558.905 us; speedup 1.0000x reference)
//
#include <hip/hip_runtime.h>
#include <hip/hip_bf16.h>

typedef __attribute__((ext_vector_type(8))) short short8;
typedef __attribute__((ext_vector_type(4))) float f32x4;
typedef __attribute__((ext_vector_type(4))) unsigned int u32x4;
typedef unsigned int u32;
typedef unsigned short u16;

#define T_STEPS 512
#define B_SZ    128
#define I_SZ    512
#define U_SZ    1024

// ws layout (bytes) — total 68,157,440 B, WELL inside the proven 80,232,448 B
#define XB_OFF   0            // X as bf16 [B][T][I] = 67,108,864 B
#define HB_OFF   67108864     // tagged h: [2][128][1024] u32 = 1,048,576 B

__device__ __forceinline__ u16 f2bf(float f) {
  u32 u = __float_as_uint(f);
  u32 r = (u + 0x7fffu + ((u >> 16) & 1u)) >> 16;   // RNE; inputs finite
  return (u16)r;
}
__device__ __forceinline__ float sigm(float x) { return 1.f / (1.f + __expf(-x)); }
__device__ __forceinline__ float tanh_s(float x) {
  float ax = fabsf(x);
  float e  = __expf(-2.f * ax);
  float t  = (1.f - e) / (1.f + e);
  return copysignf(t, x);
}

// ---- prep kernels ---------------------------------------------------------
__global__ void k_convX(const float* __restrict__ X, u16* __restrict__ Xb) {
  u32 i = blockIdx.x * 256u + threadIdx.x;            // covers 8,388,608 exactly
  float4 v = reinterpret_cast<const float4*>(X)[i];
  uint2 o;
  o.x = (u32)f2bf(v.x) | ((u32)f2bf(v.y) << 16);
  o.y = (u32)f2bf(v.z) | ((u32)f2bf(v.w) << 16);
  reinterpret_cast<uint2*>(Xb)[i] = o;
}

__global__ void k_zero(u32* __restrict__ hz) {
  u32 i = blockIdx.x * 256u + threadIdx.x;            // 1024 blocks: 262,144 u32
  hz[i] = 0u;                                         // tag 0, h = 0  (= h_{-1})
}

// ---- persistent scan ------------------------------------------------------
// 256 WGs x 512 thr, 1 WG/CU. cluster cl = wg>>6 (4 clusters x 32 batch rows,
// independent). wloc = wg&63 -> u0 = wloc*16 (64 gate-cols = 4g x 16u).
// Waves: kw = wid (8-way K split, 192 K each). Per wave 48 MFMA.
// h exchange: SELF-VALIDATING tagged u32 (tag16|bf16), pure-HIP agent atomics.
// ONE L3 round-trip per step; no flags, no polls, no store-ACK.
// W fragments converted fp32->bf16 in the prologue (no Wc staging buffer).
__global__ __launch_bounds__(512, 2)
void lstm_scan(const u16* __restrict__ Xb,
               const float* __restrict__ Wih, const float* __restrict__ Whh,
               const float* __restrict__ bih, const float* __restrict__ bhh,
               u32* __restrict__ hbuf, float* __restrict__ out) {
  __shared__ __align__(16) float gbuf[8][64][36];     // [kw][col][row32+pad]

  const int tid  = threadIdx.x;
  const int wg   = blockIdx.x;
  const int cl   = wg >> 6;                           // cluster
  const int wloc = wg & 63;
  const int rb   = cl * 32;                           // batch row base
  const int u0   = wloc * 16;                         // unit base
  const int wid  = tid >> 6;
  const int lane = tid & 63;
  const int l15  = lane & 15;
  const int kg   = lane >> 4;
  const int kw   = wid;                               // 8-way K split

  // --- persistent W fragments: direct fp32 -> bf16 conversion, pinned ---
  short8 Bf[6][4];                                    // 96 regs (VGPR/AGPR)
  #pragma unroll
  for (int ct = 0; ct < 4; ++ct) {
    const int gcol = ct * 1024 + u0 + l15;            // gate=ct, unit=u0+l15
    const float* wih_row = Wih + (size_t)gcol * I_SZ;
    const float* whh_row = Whh + (size_t)gcol * U_SZ;
    #pragma unroll
    for (int i = 0; i < 6; ++i) {
      const int k = (i * 8 + kw) * 32 + kg * 8;       // chunk<16 -> x, else h
      const float* src = (k < I_SZ) ? (wih_row + k) : (whh_row + (k - I_SZ));
      const float4 lo = *reinterpret_cast<const float4*>(src);
      const float4 hi = *reinterpret_cast<const float4*>(src + 4);
      u32x4 pk;
      pk.x = (u32)f2bf(lo.x) | ((u32)f2bf(lo.y) << 16);
      pk.y = (u32)f2bf(lo.z) | ((u32)f2bf(lo.w) << 16);
      pk.z = (u32)f2bf(hi.x) | ((u32)f2bf(hi.y) << 16);
      pk.w = (u32)f2bf(hi.z) | ((u32)f2bf(hi.w) << 16);
      Bf[i][ct] = __builtin_bit_cast(short8, pk);
      asm volatile("" : "+v"(Bf[i][ct]));             // pin: no remat/sink
    }
  }

  // --- cell ownership: thread -> (row rb+b_l, unit u0+uu) ---
  const int b_l = tid >> 4;                           // 0..31
  const int uu  = tid & 15;                           // 0..15
  const int ug  = u0 + uu;
  float bsum[4];
  #pragma unroll
  for (int g = 0; g < 4; ++g) bsum[g] = bih[g * 1024 + ug] + bhh[g * 1024 + ug];
  float c_state = 0.f;
  float* orow = out + (size_t)(rb + b_l) * (T_STEPS * U_SZ) + ug;
  const int hidx = (rb + b_l) * U_SZ + ug;

  // --- A-operand rows (per wave: 2 row-tiles) ---
  const int r0 = rb + l15;
  const int r1 = r0 + 16;
  const u16* xrow0 = Xb + (size_t)r0 * (T_STEPS * I_SZ);
  const u16* xrow1 = Xb + (size_t)r1 * (T_STEPS * I_SZ);

  // step-invariant h element offsets (u32 elements) per (ih, rt)
  int hoff[4][2];
  #pragma unroll
  for (int ih = 0; ih < 4; ++ih) {
    const int ku = ((2 + ih) * 8 + kw) * 32 + kg * 8 - 512;   // 0..1023
    hoff[ih][0] = r0 * 1024 + ku;
    hoff[ih][1] = r1 * 1024 + ku;
  }

  for (int t = 0; t < T_STEPS; ++t) {
    const u32* hsrc = hbuf + ((t & 1) ^ 1) * (B_SZ * U_SZ);
    u32*       hdst = hbuf + (t & 1) * (B_SZ * U_SZ);
    const u16* px0 = xrow0 + (size_t)t * I_SZ;
    const u16* px1 = xrow1 + (size_t)t * I_SZ;

    // ---- issue tagged h loads (pure-HIP relaxed agent atomics) ----
    u32 hv[4][2][8];
#define LOAD_HV()                                                              \
    _Pragma("unroll")                                                          \
    for (int ih = 0; ih < 4; ++ih)                                             \
      _Pragma("unroll")                                                        \
      for (int rt = 0; rt < 2; ++rt)                                           \
        _Pragma("unroll")                                                      \
        for (int j = 0; j < 8; ++j)                                            \
          hv[ih][rt][j] = __hip_atomic_load(hsrc + hoff[ih][rt] + j,           \
                              __ATOMIC_RELAXED, __HIP_MEMORY_SCOPE_AGENT);
    LOAD_HV();

    f32x4 acc[2][4];
    #pragma unroll
    for (int rt = 0; rt < 2; ++rt)
      #pragma unroll
      for (int ct = 0; ct < 4; ++ct)
        acc[rt][ct] = (f32x4){0.f, 0.f, 0.f, 0.f};

    // ---- x-phase (independent of hv; overlaps the L3 round trip) ----
    #pragma unroll
    for (int i = 0; i < 2; ++i) {
      const int k = (i * 8 + kw) * 32 + kg * 8;       // < 512
      const short8 a0 = *reinterpret_cast<const short8*>(px0 + k);
      const short8 a1 = *reinterpret_cast<const short8*>(px1 + k);
      #pragma unroll
      for (int ct = 0; ct < 4; ++ct) {
        acc[0][ct] = __builtin_amdgcn_mfma_f32_16x16x32_bf16(a0, Bf[i][ct], acc[0][ct], 0, 0, 0);
        acc[1][ct] = __builtin_amdgcn_mfma_f32_16x16x32_bf16(a1, Bf[i][ct], acc[1][ct], 0, 0, 0);
      }
    }

    // ---- validate tags (== t); retry until producers caught up ----
    const u32 texp = (u32)t << 16;
    for (;;) {
      u32 bad = 0u;
      #pragma unroll
      for (int ih = 0; ih < 4; ++ih)
        #pragma unroll
        for (int rt = 0; rt < 2; ++rt)
          #pragma unroll
          for (int j = 0; j < 8; ++j)
            bad |= hv[ih][rt][j] ^ texp;
      if (__all((int)((bad & 0xFFFF0000u) == 0u))) break;
      __builtin_amdgcn_s_sleep(1);
      LOAD_HV();
    }
#undef LOAD_HV

    // ---- unpack (low16 = bf16 h) + h-phase MFMAs ----
    #pragma unroll
    for (int ih = 0; ih < 4; ++ih)
      #pragma unroll
      for (int rt = 0; rt < 2; ++rt) {
        u32x4 pk;
        pk.x = (hv[ih][rt][0] & 0xFFFFu) | (hv[ih][rt][1] << 16);
        pk.y = (hv[ih][rt][2] & 0xFFFFu) | (hv[ih][rt][3] << 16);
        pk.z = (hv[ih][rt][4] & 0xFFFFu) | (hv[ih][rt][5] << 16);
        pk.w = (hv[ih][rt][6] & 0xFFFFu) | (hv[ih][rt][7] << 16);
        const short8 af = __builtin_bit_cast(short8, pk);
        #pragma unroll
        for (int ct = 0; ct < 4; ++ct)
          acc[rt][ct] = __builtin_amdgcn_mfma_f32_16x16x32_bf16(af, Bf[2 + ih][ct], acc[rt][ct], 0, 0, 0);
      }

    // ---- partials -> LDS (b128). C/D: col=lane&15, row=(lane>>4)*4+j ----
    #pragma unroll
    for (int rt = 0; rt < 2; ++rt)
      #pragma unroll
      for (int ct = 0; ct < 4; ++ct)
        *reinterpret_cast<float4*>(&gbuf[kw][ct * 16 + l15][rt * 16 + kg * 4]) =
            *reinterpret_cast<float4*>(&acc[rt][ct]);
    __syncthreads();                                  // (B) gbuf ready

    // ---- cell update: one (row, unit) per thread ----
    float gs[4];
    #pragma unroll
    for (int g = 0; g < 4; ++g) {
      float s = bsum[g];
      #pragma unroll
      for (int k2 = 0; k2 < 8; ++k2) s += gbuf[k2][g * 16 + uu][b_l];
      gs[g] = s;
    }
    const float ig = sigm(gs[0]);
    const float fg = sigm(gs[1]);
    const float gg = tanh_s(gs[2]);
    const float og = sigm(gs[3]);
    c_state = fg * c_state + ig * gg;
    const float h = og * tanh_s(c_state);

    // ---- publish: ONE tagged dword (drained by barrier (C)) ----
    __hip_atomic_store(hdst + hidx, ((u32)(t + 1) << 16) | (u32)f2bf(h),
                       __ATOMIC_RELAXED, __HIP_MEMORY_SCOPE_AGENT);
    orow[(size_t)t * U_SZ] = h;                       // fp32 out (plain cached)

    __syncthreads();                                  // (C) WAR-protect gbuf
  }
}

// ---- launch ---------------------------------------------------------------
extern "C" void kernel_launch(void* const* d_in, const int* in_sizes, int n_in,
                              void* d_out, int out_size, void* d_ws, size_t ws_size,
                              hipStream_t stream) {
  const float* X   = (const float*)d_in[0];
  const float* Wih = (const float*)d_in[1];
  const float* Whh = (const float*)d_in[2];
  const float* bih = (const float*)d_in[3];
  const float* bhh = (const float*)d_in[4];
  float* out = (float*)d_out;
  char*  ws  = (char*)d_ws;

  u16* Xb   = (u16*)(ws + XB_OFF);
  u32* hbuf = (u32*)(ws + HB_OFF);

  hipLaunchKernelGGL(k_convX, dim3(32768), dim3(256), 0, stream, X, Xb);
  hipLaunchKernelGGL(k_zero,  dim3(1024), dim3(256), 0, stream, hbuf);

  void* args[] = {(void*)&Xb, (void*)&Wih, (void*)&Whh, (void*)&bih, (void*)&bhh,
                  (void*)&hbuf, (void*)&out};
  hipLaunchCooperativeKernel((void*)lstm_scan, dim3(256), dim3(512), args, 0, stream);
}

// Round 14
// 6267.043 us; speedup vs baseline: 2.0040x; 2.0040x over previous
//
#include <hip/hip_runtime.h>
#include <hip/hip_bf16.h>

typedef __attribute__((ext_vector_type(8))) short short8;
typedef __attribute__((ext_vector_type(4))) float f32x4;
typedef __attribute__((ext_vector_type(4))) unsigned int u32x4;
typedef unsigned int u32;
typedef unsigned short u16;

#define T_STEPS 512
#define B_SZ    128
#define I_SZ    512
#define U_SZ    1024

// ws layout (bytes) — total 68,157,440 B (proven safe in R13)
#define XB_OFF   0            // X as bf16 [B][T][I] = 67,108,864 B
#define HB_OFF   67108864     // tagged h: [2][128][1024] u32 = 1,048,576 B

__device__ __forceinline__ u16 f2bf(float f) {
  u32 u = __float_as_uint(f);
  u32 r = (u + 0x7fffu + ((u >> 16) & 1u)) >> 16;   // RNE; inputs finite
  return (u16)r;
}
__device__ __forceinline__ float sigm(float x) { return 1.f / (1.f + __expf(-x)); }
__device__ __forceinline__ float tanh_s(float x) {
  float ax = fabsf(x);
  float e  = __expf(-2.f * ax);
  float t  = (1.f - e) / (1.f + e);
  return copysignf(t, x);
}

// ---- prep kernels ---------------------------------------------------------
__global__ void k_convX(const float* __restrict__ X, u16* __restrict__ Xb) {
  u32 i = blockIdx.x * 256u + threadIdx.x;            // covers 8,388,608 exactly
  float4 v = reinterpret_cast<const float4*>(X)[i];
  uint2 o;
  o.x = (u32)f2bf(v.x) | ((u32)f2bf(v.y) << 16);
  o.y = (u32)f2bf(v.z) | ((u32)f2bf(v.w) << 16);
  reinterpret_cast<uint2*>(Xb)[i] = o;
}

__global__ void k_zero(u32* __restrict__ hz) {
  u32 i = blockIdx.x * 256u + threadIdx.x;            // 1024 blocks: 262,144 u32
  hz[i] = 0u;                                         // tag 0, h = 0  (= h_{-1})
}

// validation: all 16 tag dwords (high16) must equal texp, wave-wide
__device__ __forceinline__ int tags_ok(const u32x4 (&hv)[4][2][2], u32 texp) {
  u32 bad = 0u;
  #pragma unroll
  for (int ih = 0; ih < 4; ++ih)
    #pragma unroll
    for (int rt = 0; rt < 2; ++rt)
      #pragma unroll
      for (int hf = 0; hf < 2; ++hf) {
        const u32x4 v = hv[ih][rt][hf];
        bad |= (v.x ^ texp) | (v.y ^ texp) | (v.z ^ texp) | (v.w ^ texp);
      }
  return __all((int)((bad & 0xFFFF0000u) == 0u));
}

// ---- persistent scan ------------------------------------------------------
// 256 WGs x 512 thr, 1 WG/CU. cluster cl = wg>>6 (4 clusters x 32 batch rows,
// independent). wloc = wg&63 -> u0 = wloc*16 (64 gate-cols = 4g x 16u).
// Waves: kw = wid (8-way K split, 192 K each). Per wave 48 MFMA.
// h exchange: SELF-VALIDATING tagged u32 (tag16|bf16) via L3 — ONE batched
// round-trip per validation round (16x dwordx4 + single vmcnt). Protocol
// correctness proven by R13; batched-asm load speed proven by R6.
__global__ __launch_bounds__(512, 2)
void lstm_scan(const u16* __restrict__ Xb,
               const float* __restrict__ Wih, const float* __restrict__ Whh,
               const float* __restrict__ bih, const float* __restrict__ bhh,
               u32* __restrict__ hbuf, float* __restrict__ out) {
  __shared__ __align__(16) float gbuf[8][64][36];     // [kw][col][row32+pad]

  const int tid  = threadIdx.x;
  const int wg   = blockIdx.x;
  const int cl   = wg >> 6;                           // cluster
  const int wloc = wg & 63;
  const int rb   = cl * 32;                           // batch row base
  const int u0   = wloc * 16;                         // unit base
  const int wid  = tid >> 6;
  const int lane = tid & 63;
  const int l15  = lane & 15;
  const int kg   = lane >> 4;
  const int kw   = wid;                               // 8-way K split

  // --- persistent W fragments: direct fp32 -> bf16 conversion, pinned ---
  short8 Bf[6][4];                                    // 96 regs (VGPR/AGPR)
  #pragma unroll
  for (int ct = 0; ct < 4; ++ct) {
    const int gcol = ct * 1024 + u0 + l15;            // gate=ct, unit=u0+l15
    const float* wih_row = Wih + (size_t)gcol * I_SZ;
    const float* whh_row = Whh + (size_t)gcol * U_SZ;
    #pragma unroll
    for (int i = 0; i < 6; ++i) {
      const int k = (i * 8 + kw) * 32 + kg * 8;       // chunk<16 -> x, else h
      const float* src = (k < I_SZ) ? (wih_row + k) : (whh_row + (k - I_SZ));
      const float4 lo = *reinterpret_cast<const float4*>(src);
      const float4 hi = *reinterpret_cast<const float4*>(src + 4);
      u32x4 pk;
      pk.x = (u32)f2bf(lo.x) | ((u32)f2bf(lo.y) << 16);
      pk.y = (u32)f2bf(lo.z) | ((u32)f2bf(lo.w) << 16);
      pk.z = (u32)f2bf(hi.x) | ((u32)f2bf(hi.y) << 16);
      pk.w = (u32)f2bf(hi.z) | ((u32)f2bf(hi.w) << 16);
      Bf[i][ct] = __builtin_bit_cast(short8, pk);
      asm volatile("" : "+v"(Bf[i][ct]));             // pin: no remat/sink
    }
  }

  // --- cell ownership: thread -> (row rb+b_l, unit u0+uu) ---
  const int b_l = tid >> 4;                           // 0..31
  const int uu  = tid & 15;                           // 0..15
  const int ug  = u0 + uu;
  float bsum[4];
  #pragma unroll
  for (int g = 0; g < 4; ++g) bsum[g] = bih[g * 1024 + ug] + bhh[g * 1024 + ug];
  float c_state = 0.f;
  float* orow = out + (size_t)(rb + b_l) * (T_STEPS * U_SZ) + ug;
  const int hidx = (rb + b_l) * U_SZ + ug;

  // --- A-operand rows (per wave: 2 row-tiles) ---
  const int r0 = rb + l15;
  const int r1 = r0 + 16;
  const u16* xrow0 = Xb + (size_t)r0 * (T_STEPS * I_SZ);
  const u16* xrow1 = Xb + (size_t)r1 * (T_STEPS * I_SZ);

  // step-invariant h element offsets (u32 elements) per (ih, rt)
  int hoff[4][2];
  #pragma unroll
  for (int ih = 0; ih < 4; ++ih) {
    const int ku = ((2 + ih) * 8 + kw) * 32 + kg * 8 - 512;   // 0..1023
    hoff[ih][0] = r0 * 1024 + ku;
    hoff[ih][1] = r1 * 1024 + ku;
  }

#define ISSUE_H()                                                              \
    _Pragma("unroll")                                                          \
    for (int ih = 0; ih < 4; ++ih)                                             \
      _Pragma("unroll")                                                        \
      for (int rt = 0; rt < 2; ++rt) {                                         \
        const u32* p = hsrc + hoff[ih][rt];                                    \
        asm volatile("global_load_dwordx4 %0, %1, off sc0 sc1"                 \
                     : "=v"(hv[ih][rt][0]) : "v"(p));                          \
        asm volatile("global_load_dwordx4 %0, %1, off sc0 sc1"                 \
                     : "=v"(hv[ih][rt][1]) : "v"(p + 4));                      \
      }
#define WAITV()                                                                \
    do { asm volatile("s_waitcnt vmcnt(0)" ::: "memory");                      \
         __builtin_amdgcn_sched_barrier(0); } while (0)

  for (int t = 0; t < T_STEPS; ++t) {
    const u32* hsrc = hbuf + ((t & 1) ^ 1) * (B_SZ * U_SZ);
    u32*       hdst = hbuf + (t & 1) * (B_SZ * U_SZ);
    const u16* px0 = xrow0 + (size_t)t * I_SZ;
    const u16* px1 = xrow1 + (size_t)t * I_SZ;

    f32x4 acc[2][4];
    #pragma unroll
    for (int rt = 0; rt < 2; ++rt)
      #pragma unroll
      for (int ct = 0; ct < 4; ++ct)
        acc[rt][ct] = (f32x4){0.f, 0.f, 0.f, 0.f};

    // ---- x-phase FIRST (compiler-managed loads, separated from asm) ----
    #pragma unroll
    for (int i = 0; i < 2; ++i) {
      const int k = (i * 8 + kw) * 32 + kg * 8;       // < 512
      const short8 a0 = *reinterpret_cast<const short8*>(px0 + k);
      const short8 a1 = *reinterpret_cast<const short8*>(px1 + k);
      #pragma unroll
      for (int ct = 0; ct < 4; ++ct) {
        acc[0][ct] = __builtin_amdgcn_mfma_f32_16x16x32_bf16(a0, Bf[i][ct], acc[0][ct], 0, 0, 0);
        acc[1][ct] = __builtin_amdgcn_mfma_f32_16x16x32_bf16(a1, Bf[i][ct], acc[1][ct], 0, 0, 0);
      }
    }

    // ---- tagged h loads: batched issue -> ONE wait -> check; retry path
    //      re-issues and re-waits BEFORE the back-edge (no in-flight regs
    //      live across any CFG edge) ----
    u32x4 hv[4][2][2];
    const u32 texp = (u32)t << 16;
    ISSUE_H();
    WAITV();
    while (!tags_ok(hv, texp)) {
      __builtin_amdgcn_s_sleep(1);
      ISSUE_H();
      WAITV();
    }

    // ---- unpack (low16 = bf16 h) + h-phase MFMAs ----
    #pragma unroll
    for (int ih = 0; ih < 4; ++ih)
      #pragma unroll
      for (int rt = 0; rt < 2; ++rt) {
        const u32x4 a = hv[ih][rt][0];
        const u32x4 b = hv[ih][rt][1];
        u32x4 pk;
        pk.x = (a.x & 0xFFFFu) | (a.y << 16);
        pk.y = (a.z & 0xFFFFu) | (a.w << 16);
        pk.z = (b.x & 0xFFFFu) | (b.y << 16);
        pk.w = (b.z & 0xFFFFu) | (b.w << 16);
        const short8 af = __builtin_bit_cast(short8, pk);
        #pragma unroll
        for (int ct = 0; ct < 4; ++ct)
          acc[rt][ct] = __builtin_amdgcn_mfma_f32_16x16x32_bf16(af, Bf[2 + ih][ct], acc[rt][ct], 0, 0, 0);
      }

    // ---- partials -> LDS (b128). C/D: col=lane&15, row=(lane>>4)*4+j ----
    #pragma unroll
    for (int rt = 0; rt < 2; ++rt)
      #pragma unroll
      for (int ct = 0; ct < 4; ++ct)
        *reinterpret_cast<float4*>(&gbuf[kw][ct * 16 + l15][rt * 16 + kg * 4]) =
            *reinterpret_cast<float4*>(&acc[rt][ct]);
    __syncthreads();                                  // (B) gbuf ready

    // ---- cell update: one (row, unit) per thread ----
    float gs[4];
    #pragma unroll
    for (int g = 0; g < 4; ++g) {
      float s = bsum[g];
      #pragma unroll
      for (int k2 = 0; k2 < 8; ++k2) s += gbuf[k2][g * 16 + uu][b_l];
      gs[g] = s;
    }
    const float ig = sigm(gs[0]);
    const float fg = sigm(gs[1]);
    const float gg = tanh_s(gs[2]);
    const float og = sigm(gs[3]);
    c_state = fg * c_state + ig * gg;
    const float h = og * tanh_s(c_state);

    // ---- publish: ONE tagged dword, fire-and-forget ----
    __hip_atomic_store(hdst + hidx, ((u32)(t + 1) << 16) | (u32)f2bf(h),
                       __ATOMIC_RELAXED, __HIP_MEMORY_SCOPE_AGENT);
    orow[(size_t)t * U_SZ] = h;                       // fp32 out (plain cached)

    __syncthreads();                                  // (C) WAR-protect gbuf
  }
#undef ISSUE_H
#undef WAITV
}

// ---- launch ---------------------------------------------------------------
extern "C" void kernel_launch(void* const* d_in, const int* in_sizes, int n_in,
                              void* d_out, int out_size, void* d_ws, size_t ws_size,
                              hipStream_t stream) {
  const float* X   = (const float*)d_in[0];
  const float* Wih = (const float*)d_in[1];
  const float* Whh = (const float*)d_in[2];
  const float* bih = (const float*)d_in[3];
  const float* bhh = (const float*)d_in[4];
  float* out = (float*)d_out;
  char*  ws  = (char*)d_ws;

  u16* Xb   = (u16*)(ws + XB_OFF);
  u32* hbuf = (u32*)(ws + HB_OFF);

  hipLaunchKernelGGL(k_convX, dim3(32768), dim3(256), 0, stream, X, Xb);
  hipLaunchKernelGGL(k_zero,  dim3(1024), dim3(256), 0, stream, hbuf);

  void* args[] = {(void*)&Xb, (void*)&Wih, (void*)&Whh, (void*)&bih, (void*)&bhh,
                  (void*)&hbuf, (void*)&out};
  hipLaunchCooperativeKernel((void*)lstm_scan, dim3(256), dim3(512), args, 0, stream);
}